// Round 3
// baseline (241.865 us; speedup 1.0000x reference)
//
#include <hip/hip_runtime.h>

// BioConvolution: 256 per-location GEMMs, C_l(64x128) = A_l(64x1024)*B_l(1024x128)+bias, ReLU
// X layout [n][h][w][ch]: float offset = n*262144 + (r*4+i)*4096 + c*256 + jh*128 + t
//   (k = i*256 + jh*128 + t, t in [0,128): each (n,i,jh) A-chunk is 512B CONTIGUOUS)
// B: Fw + l*131072 + k*128 + f (a BK=128 step for full f = 64KB contiguous)
//
// R7: HBM-efficiency round. R4/R5/R6 (demand 400/800/268 MB, occ 4/16/16 w/CU,
// barrier-free vs barriered) ALL ran at dur = FETCH(99MB)/1.25 TB/s -> the wall is
// HBM at 16% efficiency, caused by scattered 128B-granular request streams
// (A: 8 segs/instr 1MB apart; B: fh-split shredded 64KB-contiguous steps).
// Fixes: (1) full-f blocks (grid 256, 1/CU): B staging = pure 64KB sequential
// stream/step, X read once (L3 unique 262->198MB). (2) wave-per-chunk A loads:
// one 512B contiguous segment per instruction (float2/lane). (3) B row-pair in
// one lane (both rows of a kp loaded by same lane, 2x512B segs/instr) -> verified
// kp-paired LDS word layout built in-register, no shuffles. (4) raw s_barrier +
// lgkmcnt(0) only -- NO vmcnt drain, prefetch stays in flight across steps.
// LDS 102KB -> 1 block/CU. Fragment conventions verbatim from verified R6.

typedef __bf16 bf16x8 __attribute__((ext_vector_type(8)));
typedef float f32x4 __attribute__((ext_vector_type(4)));

#define SBP 140  // B LDS row stride in words: 560B = 16B-aligned, 560%128=48 -> q*4 rows land 2-way-free

__device__ __forceinline__ unsigned pack2(float a, float b) {
  __bf16 lo = (__bf16)a, hi = (__bf16)b;
  return (unsigned)__builtin_bit_cast(unsigned short, lo) |
         ((unsigned)__builtin_bit_cast(unsigned short, hi) << 16);
}

__global__ __launch_bounds__(512) void bioconv_full(
    const float* __restrict__ X, const float* __restrict__ Fw,
    const float* __restrict__ bias, float* __restrict__ out) {
  const int bx = blockIdx.x;
  // XCD-aware: XCD x gets locations x*32..x*32+31 (2 full r-groups) -> the 16
  // same-r blocks stream disjoint 1KB slices of the same X rows on one L2.
  const int l = (bx & 7) * 32 + (bx >> 3);  // 0..255
  const int r = l >> 4, c = l & 15;

  const int t = threadIdx.x;
  const int wave = t >> 6, lane = t & 63;
  const int q = lane >> 4, nl = lane & 15;
  const int m0 = (wave >> 1) * 16;  // wave's 16 output rows
  const int n0 = (wave & 1) * 64;   // wave's 64 output cols

  // A: [2][64 rows][128 k] bf16 XOR-swizzled (16KB/buf)
  // B: [2][64 kp][SBP words] kp-paired (word = B[2kp][f] | B[2kp+1][f]<<16), 35KB/buf
  __shared__ __align__(16) unsigned short As[2][64 * 128];
  __shared__ __align__(16) unsigned Bs[2][64 * SBP];

  const float* gA = X + r * 16384 + c * 256;       // + n*262144 + i*4096 + jh*128 + 2*lane
  const float* gB = Fw + (size_t)l * 131072;       // + s*16384 + k*128 + f

  float2 vA[8];           // 8 A-chunks/wave/step, one 512B-contiguous instr each
  float4 vB0[4], vB1[4];  // 4 kp-pairs/wave/step, rows 2kp & 2kp+1 in-lane

  auto loadA = [&](int s) {
    const int off = (s >> 1) * 4096 + (s & 1) * 128 + 2 * lane;  // i = s>>1, jh = s&1
#pragma unroll
    for (int m = 0; m < 8; ++m) {
      const int n = m * 8 + wave;
      vA[m] = *(const float2*)(gA + (size_t)n * 262144 + off);
    }
  };
  auto loadB = [&](int s) {
    const float* base = gB + s * 16384 + 4 * (lane & 31);
#pragma unroll
    for (int m = 0; m < 4; ++m) {
      const int kp = wave * 8 + m * 2 + (lane >> 5);  // lanes 0-31: kp even slot, 32-63: +1
      vB0[m] = *(const float4*)(base + kp * 256);        // row 2kp   (512B seg/half-wave)
      vB1[m] = *(const float4*)(base + kp * 256 + 128);  // row 2kp+1
    }
  };
  auto writeA = [&](int buf) {
    unsigned* base = (unsigned*)&As[buf][0];
#pragma unroll
    for (int m = 0; m < 8; ++m) {
      const int n = m * 8 + wave;
      // word idx = n*64 + (lane ^ ((n&7)<<2)); lane's float2 = k-local 2*lane,2*lane+1
      base[n * 64 + (lane ^ ((n & 7) << 2))] = pack2(vA[m].x, vA[m].y);
    }
  };
  auto writeB = [&](int buf) {
    unsigned* bw = (unsigned*)&Bs[buf][0] + 4 * (lane & 31);
#pragma unroll
    for (int m = 0; m < 4; ++m) {
      const int kp = wave * 8 + m * 2 + (lane >> 5);
      uint4 v;
      v.x = pack2(vB0[m].x, vB1[m].x);
      v.y = pack2(vB0[m].y, vB1[m].y);
      v.z = pack2(vB0[m].z, vB1[m].z);
      v.w = pack2(vB0[m].w, vB1[m].w);
      *(uint4*)(bw + kp * SBP) = v;  // 16B-aligned: 4*(lane&31) words + kp*560B
    }
  };

  f32x4 acc[4];
#pragma unroll
  for (int fb = 0; fb < 4; ++fb) acc[fb] = (f32x4){0.f, 0.f, 0.f, 0.f};

  auto compute = [&](int buf) {
#pragma unroll
    for (int kk = 0; kk < 4; ++kk) {
      // A-frag: lane holds A[m0+nl][kk*32 + q*8 + j] (verified R6 convention)
      const unsigned short* ap =
          &As[buf][(m0 + nl) * 128 + ((kk * 32 + q * 8) ^ ((nl & 7) << 3))];
      bf16x8 af = *(const bf16x8*)ap;
      const unsigned* bp = (const unsigned*)&Bs[buf][0] + (kk * 16 + q * 4) * SBP + n0 + nl;
#pragma unroll
      for (int fb = 0; fb < 4; ++fb) {
        const unsigned* b = bp + fb * 16;
        uint4 v;
        v.x = b[0];
        v.y = b[SBP];
        v.z = b[2 * SBP];
        v.w = b[3 * SBP];
        bf16x8 bfr = __builtin_bit_cast(bf16x8, v);
        acc[fb] = __builtin_amdgcn_mfma_f32_16x16x32_bf16(af, bfr, acc[fb], 0, 0, 0);
      }
    }
  };

  // ---- pipeline: 8 K-steps of BK=128, raw barrier (no vmcnt drain) per step ----
  loadA(0);
  loadB(0);
  writeA(0);  // reg-dep vmcnt waits only on step-0 loads
  writeB(0);
  loadA(1);
  loadB(1);
#pragma unroll
  for (int s = 0; s < 8; ++s) {
    asm volatile("s_waitcnt lgkmcnt(0)" ::: "memory");  // my LDS writes visible
    __builtin_amdgcn_s_barrier();                       // everyone's writes visible
    __builtin_amdgcn_sched_barrier(0);                  // rule #18: no hoist past wait
    compute(s & 1);
    if (s + 1 < 8) {
      writeA((s + 1) & 1);  // waits (reg-dep) loads issued at s-1; buf freed by barrier
      writeB((s + 1) & 1);
    }
    if (s + 2 < 8) {
      loadA(s + 2);  // stays in flight across next barrier (no drain)
      loadB(s + 2);
    }
  }

  // ---- epilogue: bias + ReLU; D row = m0 + q*4 + v, col = n0 + fb*16 + nl ----
#pragma unroll
  for (int fb = 0; fb < 4; ++fb) {
    const int f = n0 + fb * 16 + nl;
    const float bv = bias[f];
    float* ob = out + (size_t)l * 128 + f;
#pragma unroll
    for (int v = 0; v < 4; ++v) {
      const int row = m0 + q * 4 + v;
      ob[(size_t)row * 32768] = fmaxf(acc[fb][v] + bv, 0.f);
    }
  }
}

extern "C" void kernel_launch(void* const* d_in, const int* in_sizes, int n_in,
                              void* d_out, int out_size, void* d_ws, size_t ws_size,
                              hipStream_t stream) {
  const float* X = (const float*)d_in[0];
  const float* Fw = (const float*)d_in[1];
  const float* bias = (const float*)d_in[2];
  float* out = (float*)d_out;
  bioconv_full<<<256, 512, 0, stream>>>(X, Fw, bias, out);
}

// Round 4
// 241.624 us; speedup vs baseline: 1.0010x; 1.0010x over previous
//
#include <hip/hip_runtime.h>

// BioConvolution: 256 per-location GEMMs, C_l(64x128) = A_l(64x1024)*B_l(1024x128)+bias, ReLU
// X layout [n][h][w][ch]: float offset = n*262144 + (r*4+i)*4096 + c*256 + klocal
//   (per n, a BK=64 step (s>>2 = i, s&3 = 64-float group) is 256B CONTIGUOUS)
// B: Fw + l*131072 + k*128 + f (BK=64 step = 32KB contiguous)
//
// R8: never-drain DMA pipeline. R4-R7 (shape/occupancy/demand all varied) ALL ran
// at 85-95us = FETCH(98MB)/1.27TB/s. Common trait: VGPR-staged loads drain the
// vmem queue every step (reg-dep waits) -> avg in-flight ~4-8KB/CU (Little's law
// at 3.85 B/cy/CU). Fix: ALL staging via global_load_lds (no VGPR round-trip),
// ring-3 f32 LDS buffers (A 3x16KB + B 3x32KB = 144KB), 2-step prefetch, ONE
// counted s_waitcnt vmcnt(6)/step -> 12 load-instrs (~96KB/CU) in flight forever.
// No reg-dep vmem waits exist (compute reads f32 LDS, packs bf16 in-register).
// Rule #21 swizzle: linear LDS dest + XOR-swizzled GLOBAL source + same XOR on
// ds_read. A: 16B-chunk ^ (row&7) -> frag reads 2-way (free). B: 16B-chunk ^
// (((k>>3)&3)<<2) = f-word ^ (q<<4) -> 2-way (free).
// Ring-3 WAR: issue(s+2) clobbers buf (s-1)%3 -> placed AFTER barrier(s), and
// all waves finished compute(s-1) before barrier(s) in program order. Safe.
// MFMA fragment conventions verbatim from harness-verified R6/R7.

typedef __bf16 bf16x8 __attribute__((ext_vector_type(8)));
typedef float f32x4 __attribute__((ext_vector_type(4)));

__device__ __forceinline__ unsigned pack2(float a, float b) {
  __bf16 lo = (__bf16)a, hi = (__bf16)b;
  return (unsigned)__builtin_bit_cast(unsigned short, lo) |
         ((unsigned)__builtin_bit_cast(unsigned short, hi) << 16);
}
__device__ __forceinline__ bf16x8 cvt8(float4 lo, float4 hi) {
  uint4 v;
  v.x = pack2(lo.x, lo.y);
  v.y = pack2(lo.z, lo.w);
  v.z = pack2(hi.x, hi.y);
  v.w = pack2(hi.z, hi.w);
  return __builtin_bit_cast(bf16x8, v);
}

__device__ __forceinline__ void gl2lds16(const float* g, float* l) {
  __builtin_amdgcn_global_load_lds(
      (const __attribute__((address_space(1))) void*)g,
      (__attribute__((address_space(3))) void*)l, 16, 0, 0);
}

__global__ __launch_bounds__(512) void bioconv_dma(
    const float* __restrict__ X, const float* __restrict__ Fw,
    const float* __restrict__ bias, float* __restrict__ out) {
  const int bx = blockIdx.x;
  // XCD-aware: XCD x gets locations x*32..x*32+31.
  const int l = (bx & 7) * 32 + (bx >> 3);  // 0..255
  const int r = l >> 4, c = l & 15;

  const int t = threadIdx.x;
  const int wave = t >> 6, lane = t & 63;
  const int q = lane >> 4, nl = lane & 15;
  const int m0 = (wave >> 1) * 16;  // wave's 16 output rows
  const int n0 = (wave & 1) * 64;   // wave's 64 output cols

  // ring-3 f32 staging: A [64 n][64 k] 16KB, B [64 k][128 f] 32KB -> 144KB total
  __shared__ __align__(16) float Als[3][64 * 64];
  __shared__ __align__(16) float Bls[3][64 * 128];

  const float* gA = X + r * 16384 + c * 256;
  const float* gB = Fw + (size_t)l * 131072;

  const int arow_lo = lane >> 4;  // 0..3 (row within a 4-row A issue)
  const int achk = lane & 15;     // 16B chunk within 256B A row
  const int brow_lo = lane >> 5;  // 0..1 (row within a 2-row B wave-slice)
  const int bchk = lane & 31;     // 16B chunk within 512B B row

  // A step s: k in [s*64, s*64+64) -> per n: 256B contiguous at i=s>>2, grp=s&3.
  // Wave issues 2x (4 rows x 256B); global chunk pre-swizzled by row&7.
  auto issueA = [&](int s, int buf) {
#pragma unroll
    for (int j = 0; j < 2; ++j) {
      const int row = wave * 8 + j * 4 + arow_lo;  // n
      const int cg = achk ^ (row & 7);
      const float* g = gA + (size_t)row * 262144 + (s >> 2) * 4096 + (s & 3) * 64 + cg * 4;
      gl2lds16(g, &Als[buf][(wave * 8 + j * 4) * 64]);
    }
  };
  // B step s: 64 rows x 512B contiguous; wave issues 4x (2 rows each);
  // global chunk pre-swizzled by ((k>>3)&3)<<2 (within-row 64B granule XOR).
  auto issueB = [&](int s, int buf) {
#pragma unroll
    for (int i = 0; i < 4; ++i) {
      const int row = i * 16 + wave * 2 + brow_lo;  // k-local 0..63
      const int cswz = bchk ^ (((row >> 3) & 3) << 2);
      const float* g = gB + (size_t)(s * 64 + row) * 128 + cswz * 4;
      gl2lds16(g, &Bls[buf][(i * 16 + wave * 2) * 128]);
    }
  };

  f32x4 acc[4];
#pragma unroll
  for (int fb = 0; fb < 4; ++fb) acc[fb] = (f32x4){0.f, 0.f, 0.f, 0.f};

  auto compute = [&](int buf) {
    const float* Ab = &Als[buf][0];
    const float* Bb = &Bls[buf][0];
#pragma unroll
    for (int kk = 0; kk < 2; ++kk) {
      // A-frag: lane holds A[m0+nl][kk*32 + q*8 + j], j=0..7 (verified conv.)
      // stored chunk = global chunk ^ (row&7); row&7 = nl&7.
      const int cg = kk * 8 + q * 2;
      const int w0 = (m0 + nl) * 64 + ((cg + 0) ^ (nl & 7)) * 4;
      const int w1 = (m0 + nl) * 64 + ((cg + 1) ^ (nl & 7)) * 4;
      float4 a0 = *(const float4*)(Ab + w0);
      float4 a1 = *(const float4*)(Ab + w1);
      bf16x8 af = cvt8(a0, a1);
#pragma unroll
      for (int fb = 0; fb < 4; ++fb) {
        // B-frag: lane holds B[kk*32+q*8+j][n0+fb*16+nl]; read word = f ^ (q<<4)
        const int fw = (n0 + fb * 16 + nl) ^ (q << 4);
        const float* bp = Bb + (kk * 32 + q * 8) * 128 + fw;
        float b0 = bp[0 * 128], b1 = bp[1 * 128], b2 = bp[2 * 128], b3 = bp[3 * 128];
        float b4 = bp[4 * 128], b5 = bp[5 * 128], b6 = bp[6 * 128], b7 = bp[7 * 128];
        bf16x8 bfr = cvt8(make_float4(b0, b1, b2, b3), make_float4(b4, b5, b6, b7));
        acc[fb] = __builtin_amdgcn_mfma_f32_16x16x32_bf16(af, bfr, acc[fb], 0, 0, 0);
      }
    }
  };

  // ---- prologue: 2 steps in flight (12 vmem instrs/wave) ----
  issueA(0, 0);
  issueB(0, 0);
  issueA(1, 1);
  issueB(1, 1);

  // ---- 16 K-steps of BK=64; counted vmcnt, queue NEVER drains in main loop ----
#pragma unroll
  for (int s = 0; s < 16; ++s) {
    // my step-s loads done iff outstanding <= 6 (only step s+1 remains)
    if (s < 15)
      asm volatile("s_waitcnt vmcnt(6)" ::: "memory");
    else
      asm volatile("s_waitcnt vmcnt(0)" ::: "memory");
    __builtin_amdgcn_s_barrier();       // all waves' step-s DMA landed & visible
    __builtin_amdgcn_sched_barrier(0);  // rule #18: nothing hoists above the wait
    if (s + 2 < 16) {  // refill ring slot (s+2)%3 == (s-1)%3: readers done pre-barrier
      issueA(s + 2, (s + 2) % 3);
      issueB(s + 2, (s + 2) % 3);
    }
    compute(s % 3);
  }

  // ---- epilogue: bias + ReLU; D row = m0 + q*4 + v, col = n0 + fb*16 + nl ----
#pragma unroll
  for (int fb = 0; fb < 4; ++fb) {
    const int f = n0 + fb * 16 + nl;
    const float bv = bias[f];
    float* ob = out + (size_t)l * 128 + f;
#pragma unroll
    for (int v = 0; v < 4; ++v) {
      const int row = m0 + q * 4 + v;
      ob[(size_t)row * 32768] = fmaxf(acc[fb][v] + bv, 0.f);
    }
  }
}

extern "C" void kernel_launch(void* const* d_in, const int* in_sizes, int n_in,
                              void* d_out, int out_size, void* d_ws, size_t ws_size,
                              hipStream_t stream) {
  const float* X = (const float*)d_in[0];
  const float* Fw = (const float*)d_in[1];
  const float* bias = (const float*)d_in[2];
  float* out = (float*)d_out;
  bioconv_dma<<<256, 512, 0, stream>>>(X, Fw, bias, out);
}

// Round 5
// 240.150 us; speedup vs baseline: 1.0071x; 1.0061x over previous
//
#include <hip/hip_runtime.h>

// BioConvolution: 256 per-location GEMMs, C_l(64x128) = A_l(64x1024)*B_l(1024x128)+bias, ReLU
// X layout [n][h][w][ch]: float offset = n*262144 + (r*4+i)*4096 + c*256 + klocal
// B: Fw + l*131072 + k*128 + f (BK=64 step = 32KB contiguous)
//
// R9: DRAM channel de-phasing. R4-R8 varied shape/occupancy/in-flight/issue-path;
// ALL pinned at 201MB/~86us = 2.34 TB/s beyond-L2 (FETCH 98.5MB displayed = 64B-
// formula undercount of 197MB real). Remaining shared trait: all blocks sweep K
// in LOCKSTEP over power-of-2-strided regions (F: 512KB strides, X rows: 1MB) ->
// low address bits identical chip-wide at every instant -> HBM channel-subset
// clustering (A worst: 64 rows 1MB apart = same channel). Fix: per-block K-phase
// rotation ks = (s + 5*l) & 15 (pure accumulation reorder, f32 acc). Everything
// else (never-drain DMA ring-3, vmcnt(6), swizzles, fragments) = verified R8.

typedef __bf16 bf16x8 __attribute__((ext_vector_type(8)));
typedef float f32x4 __attribute__((ext_vector_type(4)));

__device__ __forceinline__ unsigned pack2(float a, float b) {
  __bf16 lo = (__bf16)a, hi = (__bf16)b;
  return (unsigned)__builtin_bit_cast(unsigned short, lo) |
         ((unsigned)__builtin_bit_cast(unsigned short, hi) << 16);
}
__device__ __forceinline__ bf16x8 cvt8(float4 lo, float4 hi) {
  uint4 v;
  v.x = pack2(lo.x, lo.y);
  v.y = pack2(lo.z, lo.w);
  v.z = pack2(hi.x, hi.y);
  v.w = pack2(hi.z, hi.w);
  return __builtin_bit_cast(bf16x8, v);
}

__device__ __forceinline__ void gl2lds16(const float* g, float* l) {
  __builtin_amdgcn_global_load_lds(
      (const __attribute__((address_space(1))) void*)g,
      (__attribute__((address_space(3))) void*)l, 16, 0, 0);
}

__global__ __launch_bounds__(512) void bioconv_dph(
    const float* __restrict__ X, const float* __restrict__ Fw,
    const float* __restrict__ bias, float* __restrict__ out) {
  const int bx = blockIdx.x;
  // XCD-aware: XCD x gets locations x*32..x*32+31.
  const int l = (bx & 7) * 32 + (bx >> 3);  // 0..255
  const int r = l >> 4, c = l & 15;
  const int phi = (l * 5) & 15;  // per-block K-phase (all 16 phases per 16-l group)

  const int t = threadIdx.x;
  const int wave = t >> 6, lane = t & 63;
  const int q = lane >> 4, nl = lane & 15;
  const int m0 = (wave >> 1) * 16;  // wave's 16 output rows
  const int n0 = (wave & 1) * 64;   // wave's 64 output cols

  // ring-3 f32 staging: A [64 n][64 k] 16KB, B [64 k][128 f] 32KB -> 144KB total
  __shared__ __align__(16) float Als[3][64 * 64];
  __shared__ __align__(16) float Bls[3][64 * 128];

  const float* gA = X + r * 16384 + c * 256;
  const float* gB = Fw + (size_t)l * 131072;

  const int arow_lo = lane >> 4;  // 0..3 (row within a 4-row A issue)
  const int achk = lane & 15;     // 16B chunk within 256B A row
  const int brow_lo = lane >> 5;  // 0..1 (row within a 2-row B wave-slice)
  const int bchk = lane & 31;     // 16B chunk within 512B B row

  // A chunk ks: k in [ks*64, ks*64+64) -> per n: 256B contiguous at i=ks>>2, grp=ks&3.
  auto issueA = [&](int ks, int buf) {
#pragma unroll
    for (int j = 0; j < 2; ++j) {
      const int row = wave * 8 + j * 4 + arow_lo;  // n
      const int cg = achk ^ (row & 7);
      const float* g = gA + (size_t)row * 262144 + (ks >> 2) * 4096 + (ks & 3) * 64 + cg * 4;
      gl2lds16(g, &Als[buf][(wave * 8 + j * 4) * 64]);
    }
  };
  // B chunk ks: 64 rows x 512B contiguous.
  auto issueB = [&](int ks, int buf) {
#pragma unroll
    for (int i = 0; i < 4; ++i) {
      const int row = i * 16 + wave * 2 + brow_lo;  // k-local 0..63
      const int cswz = bchk ^ (((row >> 3) & 3) << 2);
      const float* g = gB + (size_t)(ks * 64 + row) * 128 + cswz * 4;
      gl2lds16(g, &Bls[buf][(i * 16 + wave * 2) * 128]);
    }
  };

  f32x4 acc[4];
#pragma unroll
  for (int fb = 0; fb < 4; ++fb) acc[fb] = (f32x4){0.f, 0.f, 0.f, 0.f};

  auto compute = [&](int buf) {
    const float* Ab = &Als[buf][0];
    const float* Bb = &Bls[buf][0];
#pragma unroll
    for (int kk = 0; kk < 2; ++kk) {
      // A-frag: lane holds A[m0+nl][kk*32 + q*8 + j], j=0..7 (verified conv.)
      const int cg = kk * 8 + q * 2;
      const int w0 = (m0 + nl) * 64 + ((cg + 0) ^ (nl & 7)) * 4;
      const int w1 = (m0 + nl) * 64 + ((cg + 1) ^ (nl & 7)) * 4;
      float4 a0 = *(const float4*)(Ab + w0);
      float4 a1 = *(const float4*)(Ab + w1);
      bf16x8 af = cvt8(a0, a1);
#pragma unroll
      for (int fb = 0; fb < 4; ++fb) {
        // B-frag: lane holds B[kk*32+q*8+j][n0+fb*16+nl]; read word = f ^ (q<<4)
        const int fw = (n0 + fb * 16 + nl) ^ (q << 4);
        const float* bp = Bb + (kk * 32 + q * 8) * 128 + fw;
        float b0 = bp[0 * 128], b1 = bp[1 * 128], b2 = bp[2 * 128], b3 = bp[3 * 128];
        float b4 = bp[4 * 128], b5 = bp[5 * 128], b6 = bp[6 * 128], b7 = bp[7 * 128];
        bf16x8 bfr = cvt8(make_float4(b0, b1, b2, b3), make_float4(b4, b5, b6, b7));
        acc[fb] = __builtin_amdgcn_mfma_f32_16x16x32_bf16(af, bfr, acc[fb], 0, 0, 0);
      }
    }
  };

  // ---- prologue: 2 steps in flight (12 vmem instrs/wave) ----
  issueA((0 + phi) & 15, 0);
  issueB((0 + phi) & 15, 0);
  issueA((1 + phi) & 15, 1);
  issueB((1 + phi) & 15, 1);

  // ---- 16 K-steps of BK=64; counted vmcnt, queue NEVER drains in main loop ----
#pragma unroll
  for (int s = 0; s < 16; ++s) {
    // my step-s loads done iff outstanding <= 6 (only step s+1 remains)
    if (s < 15)
      asm volatile("s_waitcnt vmcnt(6)" ::: "memory");
    else
      asm volatile("s_waitcnt vmcnt(0)" ::: "memory");
    __builtin_amdgcn_s_barrier();       // all waves' step-s DMA landed & visible
    __builtin_amdgcn_sched_barrier(0);  // rule #18: nothing hoists above the wait
    if (s + 2 < 16) {  // refill ring slot (s+2)%3 == (s-1)%3: readers done pre-barrier
      issueA((s + 2 + phi) & 15, (s + 2) % 3);
      issueB((s + 2 + phi) & 15, (s + 2) % 3);
    }
    compute(s % 3);  // slot s%3 holds K-chunk (s+phi)&15; acc order-independent
  }

  // ---- epilogue: bias + ReLU; D row = m0 + q*4 + v, col = n0 + fb*16 + nl ----
#pragma unroll
  for (int fb = 0; fb < 4; ++fb) {
    const int f = n0 + fb * 16 + nl;
    const float bv = bias[f];
    float* ob = out + (size_t)l * 128 + f;
#pragma unroll
    for (int v = 0; v < 4; ++v) {
      const int row = m0 + q * 4 + v;
      ob[(size_t)row * 32768] = fmaxf(acc[fb][v] + bv, 0.f);
    }
  }
}

extern "C" void kernel_launch(void* const* d_in, const int* in_sizes, int n_in,
                              void* d_out, int out_size, void* d_ws, size_t ws_size,
                              hipStream_t stream) {
  const float* X = (const float*)d_in[0];
  const float* Fw = (const float*)d_in[1];
  const float* bias = (const float*)d_in[2];
  float* out = (float*)d_out;
  bioconv_dph<<<256, 512, 0, stream>>>(X, Fw, bias, out);
}